// Round 14
// baseline (110.073 us; speedup 1.0000x reference)
//
#include <hip/hip_runtime.h>
#include <hip/hip_bf16.h>
#include <math.h>

#define D_MODEL 768
#define HEADS 12
#define DK 64
#define SEQ 2048
#define BATCH 2
#define MTOT (BATCH * SEQ)   // 4096
#define QSCALE 0.18033688011112042f   // 0.125 * log2(e): softmax in exp2 domain

using short8 = __attribute__((ext_vector_type(8))) short;
using us4    = __attribute__((ext_vector_type(4))) unsigned short;
using us8    = __attribute__((ext_vector_type(8))) unsigned short;
using f32x4  = __attribute__((ext_vector_type(4))) float;
using f32x16 = __attribute__((ext_vector_type(16))) float;

// ---------------- helpers ---------------------------------------------------
static __device__ __forceinline__ unsigned f2bf2(float x, float y) {
    __hip_bfloat162 t = __float22bfloat162_rn(float2{x, y});
    return *reinterpret_cast<unsigned*>(&t);
}
static __device__ __forceinline__ unsigned short f2bf1(float x) {
    __hip_bfloat16 t = __float2bfloat16(x);
    return *reinterpret_cast<unsigned short*>(&t);
}
static __device__ __forceinline__ float bf2f(unsigned short u) {
    unsigned v = (unsigned)u << 16;
    return __uint_as_float(v);
}
static __device__ __forceinline__ short8 cvt8(float4 a, float4 b) {
    union { unsigned u[4]; short8 s; } r;
    r.u[0] = f2bf2(a.x, a.y);
    r.u[1] = f2bf2(a.z, a.w);
    r.u[2] = f2bf2(b.x, b.y);
    r.u[3] = f2bf2(b.z, b.w);
    return r.s;
}
static __device__ __forceinline__ float fast_exp2(float x) {
#if __has_builtin(__builtin_amdgcn_exp2f)
    return __builtin_amdgcn_exp2f(x);
#else
    return __expf(x * 0.6931471805599453f);
#endif
}
// packed f32x2 -> bf16x2: d.lo16 = bf16(lo), d.hi16 = bf16(hi)
static __device__ __forceinline__ unsigned pk2(float lo, float hi) {
    unsigned d;
    asm("v_cvt_pk_bf16_f32 %0, %1, %2" : "=v"(d) : "v"(lo), "v"(hi));
    return d;
}

static __device__ __forceinline__ void gload_lds16(const void* g, void* l) {
    __builtin_amdgcn_global_load_lds(
        (const __attribute__((address_space(1))) void*)g,
        (__attribute__((address_space(3))) void*)l, 16, 0, 0);
}

static __device__ __forceinline__ void barrier_lgkm() {
    asm volatile("s_waitcnt lgkmcnt(0)" ::: "memory");
    __builtin_amdgcn_s_barrier();
    __builtin_amdgcn_sched_barrier(0);
}
static __device__ __forceinline__ void barrier_vm0() {
    asm volatile("s_waitcnt vmcnt(0)" ::: "memory");
    __builtin_amdgcn_s_barrier();
    __builtin_amdgcn_sched_barrier(0);
}

// ---------------- pre-pass: W[k][n] fp32 -> Wt[n][k] bf16 (4 W's fused) -----
__global__ __launch_bounds__(256) void cvt_wt_k(
    const float* __restrict__ Wq, const float* __restrict__ Wk,
    const float* __restrict__ Wv, const float* __restrict__ Wo,
    unsigned short* __restrict__ Wqt, unsigned short* __restrict__ Wkt,
    unsigned short* __restrict__ Wvt, unsigned short* __restrict__ Wot)
{
    const int z = blockIdx.z;
    const float* W = z == 0 ? Wq : z == 1 ? Wk : z == 2 ? Wv : Wo;
    unsigned short* Wt = z == 0 ? Wqt : z == 1 ? Wkt : z == 2 ? Wvt : Wot;
    __shared__ float t[32][33];
    const int n0 = blockIdx.x * 32, k0 = blockIdx.y * 32;
    const int tx = threadIdx.x & 31;
    const int ty0 = (threadIdx.x >> 5) * 4;
    #pragma unroll
    for (int j = 0; j < 4; ++j)
        t[ty0 + j][tx] = W[(size_t)(k0 + ty0 + j) * D_MODEL + n0 + tx];
    __syncthreads();
    #pragma unroll
    for (int j = 0; j < 4; ++j)
        Wt[(size_t)(n0 + ty0 + j) * D_MODEL + k0 + tx] = f2bf1(t[tx][ty0 + j]);
}

// ---- QKV GEMM: 128x128 tile, BK=64, 512 thr (8 waves 2x4), 2 bufs (R9) -----
__global__ __launch_bounds__(512) void gemm_qkv_k(
    const float* __restrict__ query, const float* __restrict__ key,
    const float* __restrict__ value,
    const unsigned short* __restrict__ Wqt, const unsigned short* __restrict__ Wkt,
    const unsigned short* __restrict__ Wvt,
    const float* __restrict__ bq, const float* __restrict__ bk,
    const float* __restrict__ bv,
    unsigned short* __restrict__ qb, unsigned short* __restrict__ kb,
    unsigned short* __restrict__ vb)
{
    __shared__ __align__(16) char gsm[65536];

    const int bid = blockIdx.x;
    const int xcd = bid & 7;
    const int idx = bid >> 3;          // 0..71
    const int z   = idx / 24;
    const int rr  = idx % 24;
    const int brow = (xcd * 4 + rr / 6) * 128;
    const int bcol = (rr % 6) * 128;

    const float* A           = z == 0 ? query : z == 1 ? key : value;
    const unsigned short* Wt = z == 0 ? Wqt : z == 1 ? Wkt : Wvt;
    const float* bias        = z == 0 ? bq  : z == 1 ? bk  : bv;
    unsigned short* C        = z == 0 ? qb  : z == 1 ? kb  : vb;
    const float scale        = z == 0 ? QSCALE : 1.0f;

    const int tid  = threadIdx.x;
    const int w    = tid >> 6;
    const int lane = tid & 63;
    const int g    = lane >> 4, c = lane & 15;
    const int wr   = w >> 2, wc = w & 3;

    f32x4 acc[4][2] = {};

    const int xc  = (c & 7) << 4;
    const int rb0 = c * 128 + ((g * 16) ^ xc);
    const int rb1 = c * 128 + ((64 + g * 16) ^ xc);

    int bsrow[2], bsoff[2], bsdst[2];
    #pragma unroll
    for (int r = 0; r < 2; ++r) {
        int phys = (w * 2 + r) * 1024 + lane * 16;
        int row  = phys >> 7;
        int slot = (phys >> 4) & 7;
        bsrow[r] = row;
        bsoff[r] = (slot ^ (row & 7)) * 8;
        bsdst[r] = (w * 2 + r) * 1024;
    }
    const int ar = tid >> 2;
    const int ac = (tid & 3) << 4;
    int awa[2];
    #pragma unroll
    for (int i = 0; i < 2; ++i)
        awa[i] = ar * 128 + (((ac << 1) + 16 * i) ^ ((ar & 7) << 4));
    const float* Ap32 = A + (size_t)(brow + ar) * D_MODEL + ac;

    float4 ra0, ra1, ra2, ra3;

    auto stageB = [&](int k0, int buf) {
        #pragma unroll
        for (int r = 0; r < 2; ++r)
            gload_lds16(Wt + (size_t)(bcol + bsrow[r]) * D_MODEL + k0 + bsoff[r],
                        gsm + 32768 + buf * 16384 + bsdst[r]);
    };
    auto loadA32 = [&](int k0) {
        ra0 = *(const float4*)(Ap32 + k0);
        ra1 = *(const float4*)(Ap32 + k0 + 4);
        ra2 = *(const float4*)(Ap32 + k0 + 8);
        ra3 = *(const float4*)(Ap32 + k0 + 12);
    };
    auto writeA32 = [&](int buf) {
        *(short8*)(gsm + buf * 16384 + awa[0]) = cvt8(ra0, ra1);
        *(short8*)(gsm + buf * 16384 + awa[1]) = cvt8(ra2, ra3);
    };

    stageB(0, 0);
    loadA32(0);
    writeA32(0);
    barrier_lgkm();

    for (int k0 = 0; k0 < D_MODEL; k0 += 128) {
        #pragma unroll
        for (int u = 0; u < 2; ++u) {
            const int kn = min(k0 + u * 64 + 64, D_MODEL - 64);
            stageB(kn, u ^ 1);
            loadA32(kn);
            __builtin_amdgcn_sched_barrier(0);

            __builtin_amdgcn_s_setprio(1);
            #pragma unroll
            for (int kstep = 0; kstep < 2; ++kstep) {
                const int rb = kstep ? rb1 : rb0;
                short8 af[4], bf[2];
                #pragma unroll
                for (int m = 0; m < 4; ++m)
                    af[m] = *(const short8*)(gsm + u * 16384 + wr * 8192 +
                                             m * 2048 + rb);
                #pragma unroll
                for (int n = 0; n < 2; ++n)
                    bf[n] = *(const short8*)(gsm + 32768 + u * 16384 +
                                             wc * 4096 + n * 2048 + rb);
                #pragma unroll
                for (int m = 0; m < 4; ++m)
                    #pragma unroll
                    for (int n = 0; n < 2; ++n)
                        acc[m][n] = __builtin_amdgcn_mfma_f32_16x16x32_bf16(
                                        af[m], bf[n], acc[m][n], 0, 0, 0);
            }
            __builtin_amdgcn_s_setprio(0);

            writeA32(u ^ 1);
            barrier_lgkm();
        }
    }

    #pragma unroll
    for (int m = 0; m < 4; ++m)
        #pragma unroll
        for (int n = 0; n < 2; ++n) {
            const int col = bcol + wc * 32 + n * 16 + c;
            const float bval = bias[col];
            #pragma unroll
            for (int j = 0; j < 4; ++j) {
                const int row = brow + wr * 64 + m * 16 + g * 4 + j;
                C[(size_t)row * D_MODEL + col] = f2bf1((acc[m][n][j] + bval) * scale);
            }
        }
}

// ---- O GEMM with FUSED combine: 64x64 tile, BK=64, 256 thr, 2 bufs ---------
// A is produced on the fly: A[row][k] = a0(row,h)*op0[row][k] + a1(row,h)*op1[row][k]
// where h = k>>6 (uniform per K-step since ac<64 and k0 % 64 == 0), and
// a0/a1 are the exact flash-combine weights. Reg-staged write-late (R9 pattern).
__global__ __launch_bounds__(256) void gemm_o_k(
    const unsigned short* __restrict__ op, const float* __restrict__ mp,
    const float* __restrict__ lp, const unsigned short* __restrict__ Wt,
    const float* __restrict__ bias, float* __restrict__ C)
{
    __shared__ __align__(16) char gsm[32768];   // A: 0+buf*8192 ; B: 16384+buf*8192

    const int bid = blockIdx.x;
    const int xcd = bid & 7;
    const int idx = bid >> 3;
    const int brow = (xcd * 8 + idx / 12) * 64;
    const int bcol = (idx % 12) * 64;

    const int tid  = threadIdx.x;
    const int w    = tid >> 6;
    const int lane = tid & 63;
    const int g    = lane >> 4, c = lane & 15;
    const int wr   = w >> 1, wc = w & 1;

    f32x4 acc[2][2] = {{f32x4{0,0,0,0}, f32x4{0,0,0,0}},
                       {f32x4{0,0,0,0}, f32x4{0,0,0,0}}};

    const int xc  = (c & 7) << 4;
    const int rb0 = c * 128 + ((g * 16) ^ xc);
    const int rb1 = c * 128 + ((64 + g * 16) ^ xc);
    const int a0r = rb0 + wr * 4096, a1r = rb1 + wr * 4096;
    const int b0r = rb0 + 16384 + wc * 4096, b1r = rb1 + 16384 + wc * 4096;

    // B staging (gload_lds, linear dest + pre-swizzled source)
    int bsrow[2], bsoff[2], bsdst[2];
    #pragma unroll
    for (int r = 0; r < 2; ++r) {
        int phys = (w + 4 * r) * 1024 + lane * 16;
        int row  = phys >> 7;
        int slot = (phys >> 4) & 7;
        bsrow[r] = row;
        bsoff[r] = (slot ^ (row & 7)) * 8;
        bsdst[r] = (w + 4 * r) * 1024;
    }
    // A staging: thread owns row ar, 16 k-elems at ac (within ONE head)
    const int ar = tid >> 2;
    const int ac = (tid & 3) << 4;
    int awa[2];
    #pragma unroll
    for (int i = 0; i < 2; ++i)
        awa[i] = ar * 128 + (((ac << 1) + 16 * i) ^ ((ar & 7) << 4));
    const int arow = brow + ar;
    const unsigned short* op0 = op + (size_t)arow * D_MODEL + ac;
    const unsigned short* op1 = op0 + (size_t)MTOT * D_MODEL;

    us8 x0, x0h, x1, x1h;
    float a0f, a1f;

    auto stageB = [&](int k0, int buf) {
        #pragma unroll
        for (int r = 0; r < 2; ++r)
            gload_lds16(Wt + (size_t)(bcol + bsrow[r]) * D_MODEL + k0 + bsoff[r],
                        gsm + 16384 + buf * 8192 + bsdst[r]);
    };
    auto loadA = [&](int k0) {
        x0  = *(const us8*)(op0 + k0);
        x0h = *(const us8*)(op0 + k0 + 8);
        x1  = *(const us8*)(op1 + k0);
        x1h = *(const us8*)(op1 + k0 + 8);
        const int hh = k0 >> 6;   // head of this K-step (uniform: ac < 64)
        const float m0 = mp[(size_t)arow * HEADS + hh];
        const float m1 = mp[(size_t)MTOT * HEADS + (size_t)arow * HEADS + hh];
        const float l0 = lp[(size_t)arow * HEADS + hh];
        const float l1 = lp[(size_t)MTOT * HEADS + (size_t)arow * HEADS + hh];
        const float m  = fmaxf(m0, m1);
        const float s0 = fast_exp2(m0 - m);
        const float s1 = fast_exp2(m1 - m);
        const float inv = 1.0f / (l0 * s0 + l1 * s1);
        a0f = s0 * inv;
        a1f = s1 * inv;
    };
    auto writeA = [&](int buf) {   // reg-dep vmcnt wait retires same-step stageB
        union { unsigned u[4]; short8 s; } rA, rB;
        #pragma unroll
        for (int j = 0; j < 4; ++j) {
            rA.u[j] = f2bf2(bf2f(x0[2*j])   * a0f + bf2f(x1[2*j])   * a1f,
                            bf2f(x0[2*j+1]) * a0f + bf2f(x1[2*j+1]) * a1f);
            rB.u[j] = f2bf2(bf2f(x0h[2*j])   * a0f + bf2f(x1h[2*j])   * a1f,
                            bf2f(x0h[2*j+1]) * a0f + bf2f(x1h[2*j+1]) * a1f);
        }
        *(short8*)(gsm + buf * 8192 + awa[0]) = rA.s;
        *(short8*)(gsm + buf * 8192 + awa[1]) = rB.s;
    };

    // prologue
    stageB(0, 0);
    loadA(0);
    writeA(0);
    barrier_lgkm();

    for (int k0 = 0; k0 < D_MODEL; k0 += 128) {
        #pragma unroll
        for (int u = 0; u < 2; ++u) {
            const int kn = min(k0 + u * 64 + 64, D_MODEL - 64);   // tail dup ok
            stageB(kn, u ^ 1);
            loadA(kn);
            __builtin_amdgcn_sched_barrier(0);

            __builtin_amdgcn_s_setprio(1);
            #pragma unroll
            for (int kstep = 0; kstep < 2; ++kstep) {
                short8 af[2], bf[2];
                #pragma unroll
                for (int m = 0; m < 2; ++m)
                    af[m] = *(const short8*)(gsm + u * 8192 + m * 2048 +
                                             (kstep ? a1r : a0r));
                #pragma unroll
                for (int n = 0; n < 2; ++n)
                    bf[n] = *(const short8*)(gsm + u * 8192 + n * 2048 +
                                             (kstep ? b1r : b0r));
                #pragma unroll
                for (int m = 0; m < 2; ++m)
                    #pragma unroll
                    for (int n = 0; n < 2; ++n)
                        acc[m][n] = __builtin_amdgcn_mfma_f32_16x16x32_bf16(
                                        af[m], bf[n], acc[m][n], 0, 0, 0);
            }
            __builtin_amdgcn_s_setprio(0);

            writeA(u ^ 1);
            barrier_lgkm();
        }
    }

    #pragma unroll
    for (int m = 0; m < 2; ++m)
        #pragma unroll
        for (int n = 0; n < 2; ++n) {
            const int col = bcol + wc * 32 + n * 16 + c;
            const float bval = bias[col];
            #pragma unroll
            for (int j = 0; j < 4; ++j) {
                const int row = brow + wr * 32 + m * 16 + g * 4 + j;
                C[(size_t)row * D_MODEL + col] = acc[m][n][j] + bval;
            }
        }
}

// ---------------- Flash attention: swapped 32x32 MFMA (R11, proven) ---------
// grid 768 (XCD-chunk swz), 256 thr = 4 waves; wave w owns q-rows [q0+32w, +32).
// KV-split x2 (half). S^T = mfma(K, Q): lane (c,hi), reg r holds
// S[key=(r&3)+8(r>>2)+4hi (+32 for s1)][qrow=c].
// Key permutation pi chosen so PV A-frags are LANE-LOCAL (no cross-lane ops):
//   pi(slot 16t+8hi+2j)   = 8t+4hi+j        (lo16 of frag word j, step t)
//   pi(slot 16t+8hi+2j+1) = 32+8t+4hi+j     (hi16)
// -> frag[t].word[j] = cvt_pk(s0[4t+j], s1[4t+j]).  V^T LDS stores key k at
// position pi^-1(k); staging thread cv writes {cv,cv+32} and {cv+16,cv+48} as
// two 4B words at pos P=16(cv>>3)+8((cv>>2)&1)+2(cv&3) and P+32 (addr ^64).
// Row-max cross-half reduce = one __shfl_xor(.,32). l via ONES-MFMA.
// LDS 32KB: K: 0+buf*8192 [key][d] swz ; V^T: 16384+buf*8192 [d][pos] swz.
__global__ __launch_bounds__(256) void attn_mfma_k(
    const unsigned short* __restrict__ q, const unsigned short* __restrict__ k,
    const unsigned short* __restrict__ v, unsigned short* __restrict__ opart,
    float* __restrict__ mpart, float* __restrict__ lpart)
{
    __shared__ __align__(16) char sm[32768];

    const int tid  = threadIdx.x;
    const int w    = tid >> 6;
    const int lane = tid & 63;
    const int c    = lane & 31;
    const int hi   = lane >> 5;

    const int bid  = blockIdx.x;
    const int swz  = (bid & 7) * 96 + (bid >> 3);
    const int qt   = swz & 15;
    const int rest = swz >> 4;
    const int half = rest & 1;
    const int hb   = rest >> 1;
    const int h    = hb % HEADS;
    const int b    = hb / HEADS;
    const int q0   = qt * 128;
    const int NT2  = 16;

    // Q B-frags (pre-scaled by QSCALE): lane (c,hi) holds Q[qrow=c][16t+8hi+i]
    short8 qf[4];
    {
        const unsigned short* qp =
            q + (size_t)(b * SEQ + q0 + w * 32 + c) * D_MODEL + h * DK;
        #pragma unroll
        for (int t = 0; t < 4; ++t)
            qf[t] = *(const short8*)(qp + t * 16 + hi * 8);
    }

    float m_run = -INFINITY;
    f32x16 lacc = {};
    f32x16 o0 = {}, o1 = {};
    const short8 ONES = {0x3F80, 0x3F80, 0x3F80, 0x3F80,
                         0x3F80, 0x3F80, 0x3F80, 0x3F80};

    // hoisted frag-read offsets: addr = base + c*128 + koff[t] (row&7 == c&7)
    const int xc = (c & 7) << 4;
    int koff[4];
    #pragma unroll
    for (int t = 0; t < 4; ++t)
        koff[t] = ((32 * t + 16 * hi) ^ xc) + c * 128;

    // K staging (linear dest + pre-swizzled source)
    int kdst[2];
    const unsigned short* kg[2];
    {
        const unsigned short* kbase =
            k + (size_t)(b * SEQ + half * (SEQ / 2)) * D_MODEL + h * DK;
        #pragma unroll
        for (int r = 0; r < 2; ++r) {
            int phys = (w + 4 * r) * 1024 + lane * 16;
            int row  = phys >> 7;
            int slot = (phys >> 4) & 7;
            kdst[r]  = (w + 4 * r) * 1024;
            kg[r]    = kbase + (size_t)row * D_MODEL + (slot ^ (row & 7)) * 8;
        }
    }
    // V staging (pi-permuted positions)
    const int cv = tid & 15, vd0 = (tid >> 4) << 2;
    const int vposP = 16 * (cv >> 3) + 8 * ((cv >> 2) & 1) + 2 * (cv & 3);
    int vwa[4];
    #pragma unroll
    for (int j = 0; j < 4; ++j) {
        const int row = vd0 + j;
        vwa[j] = 16384 + row * 128 + ((2 * vposP) ^ ((row & 7) << 4));
    }
    const unsigned short* vg =
        v + (size_t)(b * SEQ + half * (SEQ / 2) + cv) * D_MODEL + h * DK + vd0;
    const int TS = 64 * D_MODEL;

    us4 va, vb_, vc, vd;

    auto issue_k = [&](int buf) {
        gload_lds16(kg[0], sm + buf * 8192 + kdst[0]);
        gload_lds16(kg[1], sm + buf * 8192 + kdst[1]);
        kg[0] += TS; kg[1] += TS;
    };
    auto load_v = [&]() {
        va  = *(const us4*)(vg);
        vb_ = *(const us4*)(vg + 16 * D_MODEL);
        vc  = *(const us4*)(vg + 32 * D_MODEL);
        vd  = *(const us4*)(vg + 48 * D_MODEL);
        vg += TS;
    };
    auto write_v = [&](int buf) {
        #pragma unroll
        for (int j = 0; j < 4; ++j) {
            unsigned lo  = (unsigned)va[j]  | ((unsigned)vc[j] << 16);  // cv, cv+32
            unsigned hi2 = (unsigned)vb_[j] | ((unsigned)vd[j] << 16);  // cv+16, cv+48
            *(unsigned*)(sm + buf * 8192 + vwa[j])        = lo;
            *(unsigned*)(sm + buf * 8192 + (vwa[j] ^ 64)) = hi2;
        }
    };

    // prologue: tile 0
    issue_k(0);
    __builtin_amdgcn_sched_barrier(0);
    load_v();
    write_v(0);
    barrier_lgkm();

    for (int kt2 = 0; kt2 < NT2; kt2 += 2) {
        #pragma unroll
        for (int u = 0; u < 2; ++u) {
            const int tile = kt2 + u;
            // prefetch tile+1 (K before V: in-order vmcnt retirement invariant)
            issue_k(u ^ 1);
            __builtin_amdgcn_sched_barrier(0);
            load_v();
            __builtin_amdgcn_sched_barrier(0);

            // ---- S^T = K @ Q^T (2 key-halves x 4 d-steps) ----
            f32x16 s0 = {}, s1 = {};
            __builtin_amdgcn_s_setprio(1);
            #pragma unroll
            for (int t = 0; t < 4; ++t) {
                short8 kf0 = *(const short8*)(sm + u * 8192 + koff[t]);
                short8 kf1 = *(const short8*)(sm + u * 8192 + 4096 + koff[t]);
                s0 = __builtin_amdgcn_mfma_f32_32x32x16_bf16(kf0, qf[t], s0, 0, 0, 0);
                s1 = __builtin_amdgcn_mfma_f32_32x32x16_bf16(kf1, qf[t], s1, 0, 0, 0);
            }
            __builtin_amdgcn_s_setprio(0);

            // ---- row max (q-row = c): in-lane + one cross-half shfl ----
            float rmax = s0[0];
            #pragma unroll
            for (int r = 1; r < 16; ++r) rmax = fmaxf(rmax, s0[r]);
            #pragma unroll
            for (int r = 0; r < 16; ++r) rmax = fmaxf(rmax, s1[r]);
            rmax = fmaxf(rmax, __shfl_xor(rmax, 32));

            if (tile == 0) {
                m_run = rmax;
            } else if (__any(rmax > m_run + 11.0f)) {
                const float mnew = fmaxf(m_run, rmax);
                const float sc = fast_exp2(m_run - mnew);
                m_run = mnew;
                #pragma unroll
                for (int r = 0; r < 16; ++r) {
                    const float scr = __shfl(sc, (r & 3) + 8 * (r >> 2) + 4 * hi);
                    lacc[r] *= scr;
                    o0[r] *= scr;
                    o1[r] *= scr;
                }
            }

            // ---- P = exp2(S - m) in place ----
            #pragma unroll
            for (int r = 0; r < 16; ++r) {
                s0[r] = fast_exp2(s0[r] - m_run);
                s1[r] = fast_exp2(s1[r] - m_run);
            }

            // ---- PV: lane-local P frags (pi-matched), O += P@V, l += P@1 ----
            __builtin_amdgcn_s_setprio(1);
            #pragma unroll
            for (int t = 0; t < 4; ++t) {
                union { unsigned u4[4]; short8 s8; } pf;
                #pragma unroll
                for (int j = 0; j < 4; ++j)
                    pf.u4[j] = pk2(s0[4 * t + j], s1[4 * t + j]);
                short8 vf0 = *(const short8*)(sm + 16384 + u * 8192 + koff[t]);
                short8 vf1 = *(const short8*)(sm + 16384 + u * 8192 + 4096 + koff[t]);
                lacc = __builtin_amdgcn_mfma_f32_32x32x16_bf16(pf.s8, ONES, lacc, 0, 0, 0);
                o0 = __builtin_amdgcn_mfma_f32_32x32x16_bf16(pf.s8, vf0, o0, 0, 0, 0);
                o1 = __builtin_amdgcn_mfma_f32_32x32x16_bf16(pf.s8, vf1, o1, 0, 0, 0);
            }
            __builtin_amdgcn_s_setprio(0);

            // ---- V(next) regs -> LDS (reg-dep retires this tile's VMEM) ----
            write_v(u ^ 1);
            barrier_lgkm();
        }
    }

    // ---- store partials: o (bf16, unnormalized), m, l ----
    const size_t obase = (size_t)half * ((size_t)MTOT * D_MODEL) +
                         (size_t)(b * SEQ) * D_MODEL + h * DK;
    #pragma unroll
    for (int r = 0; r < 16; ++r) {
        const int qrow = q0 + w * 32 + (r & 3) + 8 * (r >> 2) + 4 * hi;
        unsigned short* ob = opart + obase + (size_t)qrow * D_MODEL;
        ob[c]      = f2bf1(o0[r]);
        ob[32 + c] = f2bf1(o1[r]);
    }
    const size_t mlbase = (size_t)half * MTOT * HEADS +
                          (size_t)(b * SEQ) * HEADS + h;
    if (hi == 0)
        mpart[mlbase + (size_t)(q0 + w * 32 + c) * HEADS] = m_run;
    if (c == 0) {
        #pragma unroll
        for (int r = 0; r < 16; ++r) {
            const int qrow = q0 + w * 32 + (r & 3) + 8 * (r >> 2) + 4 * hi;
            lpart[mlbase + (size_t)qrow * HEADS] = lacc[r];
        }
    }
}

// ---------------------------------------------------------------------------
extern "C" void kernel_launch(void* const* d_in, const int* in_sizes, int n_in,
                              void* d_out, int out_size, void* d_ws, size_t ws_size,
                              hipStream_t stream) {
    const float* query = (const float*)d_in[0];
    const float* key   = (const float*)d_in[1];
    const float* value = (const float*)d_in[2];
    const float* Wq = (const float*)d_in[3];
    const float* bq = (const float*)d_in[4];
    const float* Wk = (const float*)d_in[5];
    const float* bk = (const float*)d_in[6];
    const float* Wv = (const float*)d_in[7];
    const float* bv = (const float*)d_in[8];
    const float* Wo = (const float*)d_in[9];
    const float* bo = (const float*)d_in[10];
    float* out = (float*)d_out;

    const size_t mat = (size_t)MTOT * D_MODEL;      // 3.145M elems
    // ws layout identical to the proven R11 kernel (cb slot now unused).
    unsigned short* qb  = (unsigned short*)d_ws;    // projected Q/K/V (bf16)
    unsigned short* kb  = qb + mat;
    unsigned short* vb  = kb + mat;
    unsigned short* cb  = vb + mat;                 // (unused after fusion)
    unsigned short* Wqt = cb + mat;                 // transposed bf16 weights
    unsigned short* Wkt = Wqt + (size_t)D_MODEL * D_MODEL;
    unsigned short* Wvt = Wkt + (size_t)D_MODEL * D_MODEL;
    unsigned short* Wot = Wvt + (size_t)D_MODEL * D_MODEL;
    unsigned short* op  = Wot + (size_t)D_MODEL * D_MODEL;   // o partials x2
    float*          mp  = (float*)(op + 2 * mat);            // m partials x2
    float*          lp  = mp + 2 * (size_t)MTOT * HEADS;     // l partials x2
    (void)cb;

    cvt_wt_k<<<dim3(D_MODEL / 32, D_MODEL / 32, 4), 256, 0, stream>>>(
        Wq, Wk, Wv, Wo, Wqt, Wkt, Wvt, Wot);

    gemm_qkv_k<<<dim3(576), 512, 0, stream>>>(
        query, key, value, Wqt, Wkt, Wvt, bq, bk, bv, qb, kb, vb);

    attn_mfma_k<<<dim3(768), 256, 0, stream>>>(qb, kb, vb, op, mp, lp);

    gemm_o_k<<<dim3(768), 256, 0, stream>>>(op, mp, lp, Wot, bo, out);
}

// Round 16
// 102.766 us; speedup vs baseline: 1.0711x; 1.0711x over previous
//
#include <hip/hip_runtime.h>
#include <hip/hip_bf16.h>
#include <math.h>

#define D_MODEL 768
#define HEADS 12
#define DK 64
#define SEQ 2048
#define BATCH 2
#define MTOT (BATCH * SEQ)   // 4096
#define QSCALE 0.18033688011112042f   // 0.125 * log2(e): softmax in exp2 domain

using short8 = __attribute__((ext_vector_type(8))) short;
using us4    = __attribute__((ext_vector_type(4))) unsigned short;
using us8    = __attribute__((ext_vector_type(8))) unsigned short;
using f32x4  = __attribute__((ext_vector_type(4))) float;
using f32x16 = __attribute__((ext_vector_type(16))) float;

// ---------------- helpers ---------------------------------------------------
static __device__ __forceinline__ unsigned f2bf2(float x, float y) {
    __hip_bfloat162 t = __float22bfloat162_rn(float2{x, y});
    return *reinterpret_cast<unsigned*>(&t);
}
static __device__ __forceinline__ unsigned short f2bf1(float x) {
    __hip_bfloat16 t = __float2bfloat16(x);
    return *reinterpret_cast<unsigned short*>(&t);
}
static __device__ __forceinline__ float bf2f(unsigned short u) {
    unsigned v = (unsigned)u << 16;
    return __uint_as_float(v);
}
static __device__ __forceinline__ short8 cvt8(float4 a, float4 b) {
    union { unsigned u[4]; short8 s; } r;
    r.u[0] = f2bf2(a.x, a.y);
    r.u[1] = f2bf2(a.z, a.w);
    r.u[2] = f2bf2(b.x, b.y);
    r.u[3] = f2bf2(b.z, b.w);
    return r.s;
}
static __device__ __forceinline__ float fast_exp2(float x) {
#if __has_builtin(__builtin_amdgcn_exp2f)
    return __builtin_amdgcn_exp2f(x);
#else
    return __expf(x * 0.6931471805599453f);
#endif
}
// packed f32x2 -> bf16x2: d.lo16 = bf16(lo), d.hi16 = bf16(hi)
static __device__ __forceinline__ unsigned pk2(float lo, float hi) {
    unsigned d;
    asm("v_cvt_pk_bf16_f32 %0, %1, %2" : "=v"(d) : "v"(lo), "v"(hi));
    return d;
}

static __device__ __forceinline__ void gload_lds16(const void* g, void* l) {
    __builtin_amdgcn_global_load_lds(
        (const __attribute__((address_space(1))) void*)g,
        (__attribute__((address_space(3))) void*)l, 16, 0, 0);
}

static __device__ __forceinline__ void barrier_lgkm() {
    asm volatile("s_waitcnt lgkmcnt(0)" ::: "memory");
    __builtin_amdgcn_s_barrier();
    __builtin_amdgcn_sched_barrier(0);
}
static __device__ __forceinline__ void barrier_vm0() {
    asm volatile("s_waitcnt vmcnt(0)" ::: "memory");
    __builtin_amdgcn_s_barrier();
    __builtin_amdgcn_sched_barrier(0);
}

// ---------------- pre-pass: W[k][n] fp32 -> Wt[n][k] bf16 (4 W's fused) -----
__global__ __launch_bounds__(256) void cvt_wt_k(
    const float* __restrict__ Wq, const float* __restrict__ Wk,
    const float* __restrict__ Wv, const float* __restrict__ Wo,
    unsigned short* __restrict__ Wqt, unsigned short* __restrict__ Wkt,
    unsigned short* __restrict__ Wvt, unsigned short* __restrict__ Wot)
{
    const int z = blockIdx.z;
    const float* W = z == 0 ? Wq : z == 1 ? Wk : z == 2 ? Wv : Wo;
    unsigned short* Wt = z == 0 ? Wqt : z == 1 ? Wkt : z == 2 ? Wvt : Wot;
    __shared__ float t[32][33];
    const int n0 = blockIdx.x * 32, k0 = blockIdx.y * 32;
    const int tx = threadIdx.x & 31;
    const int ty0 = (threadIdx.x >> 5) * 4;
    #pragma unroll
    for (int j = 0; j < 4; ++j)
        t[ty0 + j][tx] = W[(size_t)(k0 + ty0 + j) * D_MODEL + n0 + tx];
    __syncthreads();
    #pragma unroll
    for (int j = 0; j < 4; ++j)
        Wt[(size_t)(n0 + ty0 + j) * D_MODEL + k0 + tx] = f2bf1(t[tx][ty0 + j]);
}

// ---- QKV GEMM: 128x128 tile, BK=64, 512 thr (8 waves 2x4), 2 bufs ----------
// Distance-2 prefetch, ALL loads reg-staged (single VMEM class; every wait is
// an exact compiler register dependency — no counted-vmcnt assumptions).
// Step n: issue A/B(n+2) loads -> MFMA(buf n&1) -> ds_write A/B(n+1) from the
// OTHER named reg set (loads a full step old -> no stall) -> lgkm barrier.
__global__ __launch_bounds__(512) void gemm_qkv_k(
    const float* __restrict__ query, const float* __restrict__ key,
    const float* __restrict__ value,
    const unsigned short* __restrict__ Wqt, const unsigned short* __restrict__ Wkt,
    const unsigned short* __restrict__ Wvt,
    const float* __restrict__ bq, const float* __restrict__ bk,
    const float* __restrict__ bv,
    unsigned short* __restrict__ qb, unsigned short* __restrict__ kb,
    unsigned short* __restrict__ vb)
{
    __shared__ __align__(16) char gsm[65536];   // A: 0+buf*16384 ; B: 32768+buf*16384

    const int bid = blockIdx.x;
    const int xcd = bid & 7;
    const int idx = bid >> 3;          // 0..71
    const int z   = idx / 24;
    const int rr  = idx % 24;
    const int brow = (xcd * 4 + rr / 6) * 128;
    const int bcol = (rr % 6) * 128;

    const float* A           = z == 0 ? query : z == 1 ? key : value;
    const unsigned short* Wt = z == 0 ? Wqt : z == 1 ? Wkt : Wvt;
    const float* bias        = z == 0 ? bq  : z == 1 ? bk  : bv;
    unsigned short* C        = z == 0 ? qb  : z == 1 ? kb  : vb;
    const float scale        = z == 0 ? QSCALE : 1.0f;

    const int tid  = threadIdx.x;
    const int w    = tid >> 6;
    const int lane = tid & 63;
    const int g    = lane >> 4, c = lane & 15;
    const int wr   = w >> 2, wc = w & 3;

    f32x4 acc[4][2] = {};

    const int xc  = (c & 7) << 4;
    const int rb0 = c * 128 + ((g * 16) ^ xc);
    const int rb1 = c * 128 + ((64 + g * 16) ^ xc);

    // A staging: thread owns row ar, 16 k-elems at ac (fp32 -> bf16 cvt)
    const int ar = tid >> 2;
    const int ac = (tid & 3) << 4;
    int awa[2];
    #pragma unroll
    for (int i = 0; i < 2; ++i)
        awa[i] = ar * 128 + (((ac << 1) + 16 * i) ^ ((ar & 7) << 4));
    const float* Ap32 = A + (size_t)(brow + ar) * D_MODEL + ac;

    // B staging: thread owns row br2 (n-dim), logical 16B slots bs2, bs2+1
    // LDS mapping matches the MFMA read swizzle: logical slot l -> phys l^(row&7)
    const int br2 = tid >> 2;            // 0..127
    const int bs2 = (tid & 3) << 1;      // 0,2,4,6
    int bwa[2];
    #pragma unroll
    for (int i = 0; i < 2; ++i)
        bwa[i] = 32768 + br2 * 128 + (((bs2 + i) ^ (br2 & 7)) << 4);
    const unsigned short* WtB = Wt + (size_t)(bcol + br2) * D_MODEL + bs2 * 8;

    // two named reg sets (rule #20: compile-time indexed via unrolled u)
    float4 rA0[4], rA1[4];
    us8    rB0[2], rB1[2];

    auto loadA0 = [&](int k0) {
        rA0[0] = *(const float4*)(Ap32 + k0);
        rA0[1] = *(const float4*)(Ap32 + k0 + 4);
        rA0[2] = *(const float4*)(Ap32 + k0 + 8);
        rA0[3] = *(const float4*)(Ap32 + k0 + 12);
    };
    auto loadA1 = [&](int k0) {
        rA1[0] = *(const float4*)(Ap32 + k0);
        rA1[1] = *(const float4*)(Ap32 + k0 + 4);
        rA1[2] = *(const float4*)(Ap32 + k0 + 8);
        rA1[3] = *(const float4*)(Ap32 + k0 + 12);
    };
    auto loadB0 = [&](int k0) {
        rB0[0] = *(const us8*)(WtB + k0);
        rB0[1] = *(const us8*)(WtB + k0 + 8);
    };
    auto loadB1 = [&](int k0) {
        rB1[0] = *(const us8*)(WtB + k0);
        rB1[1] = *(const us8*)(WtB + k0 + 8);
    };
    auto writeA0 = [&](int buf) {
        *(short8*)(gsm + buf * 16384 + awa[0]) = cvt8(rA0[0], rA0[1]);
        *(short8*)(gsm + buf * 16384 + awa[1]) = cvt8(rA0[2], rA0[3]);
    };
    auto writeA1 = [&](int buf) {
        *(short8*)(gsm + buf * 16384 + awa[0]) = cvt8(rA1[0], rA1[1]);
        *(short8*)(gsm + buf * 16384 + awa[1]) = cvt8(rA1[2], rA1[3]);
    };
    auto writeB0 = [&](int buf) {
        *(us8*)(gsm + buf * 16384 + bwa[0]) = rB0[0];
        *(us8*)(gsm + buf * 16384 + bwa[1]) = rB0[1];
    };
    auto writeB1 = [&](int buf) {
        *(us8*)(gsm + buf * 16384 + bwa[0]) = rB1[0];
        *(us8*)(gsm + buf * 16384 + bwa[1]) = rB1[1];
    };

    // prologue: tiles 0,1 -> reg sets 0,1; write tile 0 -> buf 0
    loadA0(0);  loadB0(0);
    loadA1(64); loadB1(64);
    writeA0(0); writeB0(0);   // exact reg-dep waits for tile-0 loads only
    barrier_lgkm();           // tile-1 loads stay in flight

    // 12 K-steps; step n (u = n&1 compile-time):
    //   issue tile n+2 loads into set u; MFMA(buf u);
    //   ds_write tile n+1 from set u^1 (reg-dep: loads one full step old);
    //   lgkm barrier (drains ds_writes; no vmcnt).
    for (int iter = 0; iter < 6; ++iter) {
        #pragma unroll
        for (int u = 0; u < 2; ++u) {
            const int n   = 2 * iter + u;
            const int kb2 = min(n + 2, 11) * 64;   // tail dup: harmless
            if (u == 0) { loadA0(kb2); loadB0(kb2); }
            else        { loadA1(kb2); loadB1(kb2); }
            __builtin_amdgcn_sched_barrier(0);

            __builtin_amdgcn_s_setprio(1);
            #pragma unroll
            for (int kstep = 0; kstep < 2; ++kstep) {
                const int rb = kstep ? rb1 : rb0;
                short8 af[4], bf[2];
                #pragma unroll
                for (int m = 0; m < 4; ++m)
                    af[m] = *(const short8*)(gsm + u * 16384 + wr * 8192 +
                                             m * 2048 + rb);
                #pragma unroll
                for (int nn = 0; nn < 2; ++nn)
                    bf[nn] = *(const short8*)(gsm + 32768 + u * 16384 +
                                              wc * 4096 + nn * 2048 + rb);
                #pragma unroll
                for (int m = 0; m < 4; ++m)
                    #pragma unroll
                    for (int nn = 0; nn < 2; ++nn)
                        acc[m][nn] = __builtin_amdgcn_mfma_f32_16x16x32_bf16(
                                         af[m], bf[nn], acc[m][nn], 0, 0, 0);
            }
            __builtin_amdgcn_s_setprio(0);
            __builtin_amdgcn_sched_barrier(0);   // keep writes after MFMAs

            if (u == 0) { writeA1(1); writeB1(1); }   // tile n+1 -> buf 1
            else        { writeA0(0); writeB0(0); }   // tile n+1 -> buf 0
            barrier_lgkm();
        }
    }

    #pragma unroll
    for (int m = 0; m < 4; ++m)
        #pragma unroll
        for (int n = 0; n < 2; ++n) {
            const int col = bcol + wc * 32 + n * 16 + c;
            const float bval = bias[col];
            #pragma unroll
            for (int j = 0; j < 4; ++j) {
                const int row = brow + wr * 64 + m * 16 + g * 4 + j;
                C[(size_t)row * D_MODEL + col] = f2bf1((acc[m][n][j] + bval) * scale);
            }
        }
}

// ---- O GEMM: 64x64 tile, BK=64, 256 thr, 2 bufs (R11 proven) ---------------
__global__ __launch_bounds__(256) void gemm_o_k(
    const unsigned short* __restrict__ A, const unsigned short* __restrict__ Wt,
    const float* __restrict__ bias, float* __restrict__ C)
{
    __shared__ __align__(16) char gsm[32768];

    const int bid = blockIdx.x;
    const int xcd = bid & 7;
    const int idx = bid >> 3;
    const int brow = (xcd * 8 + idx / 12) * 64;
    const int bcol = (idx % 12) * 64;

    const int tid  = threadIdx.x;
    const int w    = tid >> 6;
    const int lane = tid & 63;
    const int g    = lane >> 4, c = lane & 15;
    const int wr   = w >> 1, wc = w & 1;

    f32x4 acc[2][2] = {{f32x4{0,0,0,0}, f32x4{0,0,0,0}},
                       {f32x4{0,0,0,0}, f32x4{0,0,0,0}}};

    const int xc  = (c & 7) << 4;
    const int rb0 = c * 128 + ((g * 16) ^ xc);
    const int rb1 = c * 128 + ((64 + g * 16) ^ xc);
    const int a0 = rb0 + wr * 4096, a1 = rb1 + wr * 4096;
    const int b0r = rb0 + 16384 + wc * 4096, b1r = rb1 + 16384 + wc * 4096;

    int bsrow[2], bsoff[2], bsdst[2];
    #pragma unroll
    for (int r = 0; r < 2; ++r) {
        int phys = (w + 4 * r) * 1024 + lane * 16;
        int row  = phys >> 7;
        int slot = (phys >> 4) & 7;
        bsrow[r] = row;
        bsoff[r] = (slot ^ (row & 7)) * 8;
        bsdst[r] = (w + 4 * r) * 1024;
    }

    auto stage = [&](int k0, int buf) {
        #pragma unroll
        for (int r = 0; r < 2; ++r) {
            gload_lds16(A  + (size_t)(brow + bsrow[r]) * D_MODEL + k0 + bsoff[r],
                        gsm + buf * 8192 + bsdst[r]);
            gload_lds16(Wt + (size_t)(bcol + bsrow[r]) * D_MODEL + k0 + bsoff[r],
                        gsm + 16384 + buf * 8192 + bsdst[r]);
        }
    };

    stage(0, 0);
    barrier_vm0();

    for (int k0 = 0; k0 < D_MODEL; k0 += 128) {
        #pragma unroll
        for (int u = 0; u < 2; ++u) {
            const int kn = min(k0 + u * 64 + 64, D_MODEL - 64);
            stage(kn, u ^ 1);
            __builtin_amdgcn_sched_barrier(0);

            #pragma unroll
            for (int kstep = 0; kstep < 2; ++kstep) {
                short8 af[2], bf[2];
                #pragma unroll
                for (int m = 0; m < 2; ++m)
                    af[m] = *(const short8*)(gsm + u * 8192 + m * 2048 +
                                             (kstep ? a1 : a0));
                #pragma unroll
                for (int n = 0; n < 2; ++n)
                    bf[n] = *(const short8*)(gsm + u * 8192 + n * 2048 +
                                             (kstep ? b1r : b0r));
                #pragma unroll
                for (int m = 0; m < 2; ++m)
                    #pragma unroll
                    for (int n = 0; n < 2; ++n)
                        acc[m][n] = __builtin_amdgcn_mfma_f32_16x16x32_bf16(
                                        af[m], bf[n], acc[m][n], 0, 0, 0);
            }
            barrier_vm0();
        }
    }

    #pragma unroll
    for (int m = 0; m < 2; ++m)
        #pragma unroll
        for (int n = 0; n < 2; ++n) {
            const int col = bcol + wc * 32 + n * 16 + c;
            const float bval = bias[col];
            #pragma unroll
            for (int j = 0; j < 4; ++j) {
                const int row = brow + wr * 32 + m * 16 + g * 4 + j;
                C[(size_t)row * D_MODEL + col] = acc[m][n][j] + bval;
            }
        }
}

// ---------------- Flash attention: swapped 32x32 MFMA (R11, proven) ---------
__global__ __launch_bounds__(256) void attn_mfma_k(
    const unsigned short* __restrict__ q, const unsigned short* __restrict__ k,
    const unsigned short* __restrict__ v, unsigned short* __restrict__ opart,
    float* __restrict__ mpart, float* __restrict__ lpart)
{
    __shared__ __align__(16) char sm[32768];

    const int tid  = threadIdx.x;
    const int w    = tid >> 6;
    const int lane = tid & 63;
    const int c    = lane & 31;
    const int hi   = lane >> 5;

    const int bid  = blockIdx.x;
    const int swz  = (bid & 7) * 96 + (bid >> 3);
    const int qt   = swz & 15;
    const int rest = swz >> 4;
    const int half = rest & 1;
    const int hb   = rest >> 1;
    const int h    = hb % HEADS;
    const int b    = hb / HEADS;
    const int q0   = qt * 128;
    const int NT2  = 16;

    short8 qf[4];
    {
        const unsigned short* qp =
            q + (size_t)(b * SEQ + q0 + w * 32 + c) * D_MODEL + h * DK;
        #pragma unroll
        for (int t = 0; t < 4; ++t)
            qf[t] = *(const short8*)(qp + t * 16 + hi * 8);
    }

    float m_run = -INFINITY;
    f32x16 lacc = {};
    f32x16 o0 = {}, o1 = {};
    const short8 ONES = {0x3F80, 0x3F80, 0x3F80, 0x3F80,
                         0x3F80, 0x3F80, 0x3F80, 0x3F80};

    const int xc = (c & 7) << 4;
    int koff[4];
    #pragma unroll
    for (int t = 0; t < 4; ++t)
        koff[t] = ((32 * t + 16 * hi) ^ xc) + c * 128;

    int kdst[2];
    const unsigned short* kg[2];
    {
        const unsigned short* kbase =
            k + (size_t)(b * SEQ + half * (SEQ / 2)) * D_MODEL + h * DK;
        #pragma unroll
        for (int r = 0; r < 2; ++r) {
            int phys = (w + 4 * r) * 1024 + lane * 16;
            int row  = phys >> 7;
            int slot = (phys >> 4) & 7;
            kdst[r]  = (w + 4 * r) * 1024;
            kg[r]    = kbase + (size_t)row * D_MODEL + (slot ^ (row & 7)) * 8;
        }
    }
    const int cv = tid & 15, vd0 = (tid >> 4) << 2;
    const int vposP = 16 * (cv >> 3) + 8 * ((cv >> 2) & 1) + 2 * (cv & 3);
    int vwa[4];
    #pragma unroll
    for (int j = 0; j < 4; ++j) {
        const int row = vd0 + j;
        vwa[j] = 16384 + row * 128 + ((2 * vposP) ^ ((row & 7) << 4));
    }
    const unsigned short* vg =
        v + (size_t)(b * SEQ + half * (SEQ / 2) + cv) * D_MODEL + h * DK + vd0;
    const int TS = 64 * D_MODEL;

    us4 va, vb_, vc, vd;

    auto issue_k = [&](int buf) {
        gload_lds16(kg[0], sm + buf * 8192 + kdst[0]);
        gload_lds16(kg[1], sm + buf * 8192 + kdst[1]);
        kg[0] += TS; kg[1] += TS;
    };
    auto load_v = [&]() {
        va  = *(const us4*)(vg);
        vb_ = *(const us4*)(vg + 16 * D_MODEL);
        vc  = *(const us4*)(vg + 32 * D_MODEL);
        vd  = *(const us4*)(vg + 48 * D_MODEL);
        vg += TS;
    };
    auto write_v = [&](int buf) {
        #pragma unroll
        for (int j = 0; j < 4; ++j) {
            unsigned lo  = (unsigned)va[j]  | ((unsigned)vc[j] << 16);  // cv, cv+32
            unsigned hi2 = (unsigned)vb_[j] | ((unsigned)vd[j] << 16);  // cv+16, cv+48
            *(unsigned*)(sm + buf * 8192 + vwa[j])        = lo;
            *(unsigned*)(sm + buf * 8192 + (vwa[j] ^ 64)) = hi2;
        }
    };

    issue_k(0);
    __builtin_amdgcn_sched_barrier(0);
    load_v();
    write_v(0);
    barrier_lgkm();

    for (int kt2 = 0; kt2 < NT2; kt2 += 2) {
        #pragma unroll
        for (int u = 0; u < 2; ++u) {
            const int tile = kt2 + u;
            issue_k(u ^ 1);
            __builtin_amdgcn_sched_barrier(0);
            load_v();
            __builtin_amdgcn_sched_barrier(0);

            f32x16 s0 = {}, s1 = {};
            __builtin_amdgcn_s_setprio(1);
            #pragma unroll
            for (int t = 0; t < 4; ++t) {
                short8 kf0 = *(const short8*)(sm + u * 8192 + koff[t]);
                short8 kf1 = *(const short8*)(sm + u * 8192 + 4096 + koff[t]);
                s0 = __builtin_amdgcn_mfma_f32_32x32x16_bf16(kf0, qf[t], s0, 0, 0, 0);
                s1 = __builtin_amdgcn_mfma_f32_32x32x16_bf16(kf1, qf[t], s1, 0, 0, 0);
            }
            __builtin_amdgcn_s_setprio(0);

            float rmax = s0[0];
            #pragma unroll
            for (int r = 1; r < 16; ++r) rmax = fmaxf(rmax, s0[r]);
            #pragma unroll
            for (int r = 0; r < 16; ++r) rmax = fmaxf(rmax, s1[r]);
            rmax = fmaxf(rmax, __shfl_xor(rmax, 32));

            if (tile == 0) {
                m_run = rmax;
            } else if (__any(rmax > m_run + 11.0f)) {
                const float mnew = fmaxf(m_run, rmax);
                const float sc = fast_exp2(m_run - mnew);
                m_run = mnew;
                #pragma unroll
                for (int r = 0; r < 16; ++r) {
                    const float scr = __shfl(sc, (r & 3) + 8 * (r >> 2) + 4 * hi);
                    lacc[r] *= scr;
                    o0[r] *= scr;
                    o1[r] *= scr;
                }
            }

            #pragma unroll
            for (int r = 0; r < 16; ++r) {
                s0[r] = fast_exp2(s0[r] - m_run);
                s1[r] = fast_exp2(s1[r] - m_run);
            }

            __builtin_amdgcn_s_setprio(1);
            #pragma unroll
            for (int t = 0; t < 4; ++t) {
                union { unsigned u4[4]; short8 s8; } pf;
                #pragma unroll
                for (int j = 0; j < 4; ++j)
                    pf.u4[j] = pk2(s0[4 * t + j], s1[4 * t + j]);
                short8 vf0 = *(const short8*)(sm + 16384 + u * 8192 + koff[t]);
                short8 vf1 = *(const short8*)(sm + 16384 + u * 8192 + 4096 + koff[t]);
                lacc = __builtin_amdgcn_mfma_f32_32x32x16_bf16(pf.s8, ONES, lacc, 0, 0, 0);
                o0 = __builtin_amdgcn_mfma_f32_32x32x16_bf16(pf.s8, vf0, o0, 0, 0, 0);
                o1 = __builtin_amdgcn_mfma_f32_32x32x16_bf16(pf.s8, vf1, o1, 0, 0, 0);
            }
            __builtin_amdgcn_s_setprio(0);

            write_v(u ^ 1);
            barrier_lgkm();
        }
    }

    const size_t obase = (size_t)half * ((size_t)MTOT * D_MODEL) +
                         (size_t)(b * SEQ) * D_MODEL + h * DK;
    #pragma unroll
    for (int r = 0; r < 16; ++r) {
        const int qrow = q0 + w * 32 + (r & 3) + 8 * (r >> 2) + 4 * hi;
        unsigned short* ob = opart + obase + (size_t)qrow * D_MODEL;
        ob[c]      = f2bf1(o0[r]);
        ob[32 + c] = f2bf1(o1[r]);
    }
    const size_t mlbase = (size_t)half * MTOT * HEADS +
                          (size_t)(b * SEQ) * HEADS + h;
    if (hi == 0)
        mpart[mlbase + (size_t)(q0 + w * 32 + c) * HEADS] = m_run;
    if (c == 0) {
        #pragma unroll
        for (int r = 0; r < 16; ++r) {
            const int qrow = q0 + w * 32 + (r & 3) + 8 * (r >> 2) + 4 * hi;
            lpart[mlbase + (size_t)qrow * HEADS] = lacc[r];
        }
    }
}

// ---------------- combine: merge the two KV-halves exactly (R11) ------------
__global__ __launch_bounds__(256) void combine_k(
    const unsigned short* __restrict__ op, const float* __restrict__ mp,
    const float* __restrict__ lp, unsigned short* __restrict__ cb)
{
    const int t   = blockIdx.x * 256 + threadIdx.x;
    const int row = t / 96;
    const int gi  = t - row * 96;
    const int col = gi << 3;
    const int h   = gi >> 3;

    const float m0 = mp[(size_t)row * HEADS + h];
    const float m1 = mp[(size_t)MTOT * HEADS + (size_t)row * HEADS + h];
    const float l0 = lp[(size_t)row * HEADS + h];
    const float l1 = lp[(size_t)MTOT * HEADS + (size_t)row * HEADS + h];
    const float m  = fmaxf(m0, m1);
    const float s0 = fast_exp2(m0 - m);
    const float s1 = fast_exp2(m1 - m);
    const float inv = 1.0f / (l0 * s0 + l1 * s1);
    const float a0 = s0 * inv, a1 = s1 * inv;

    const size_t off = (size_t)row * D_MODEL + col;
    us4 x0  = *(const us4*)(op + off);
    us4 x0b = *(const us4*)(op + off + 4);
    us4 x1  = *(const us4*)(op + (size_t)MTOT * D_MODEL + off);
    us4 x1b = *(const us4*)(op + (size_t)MTOT * D_MODEL + off + 4);

    union { unsigned short u[8]; short8 s; } r;
    #pragma unroll
    for (int j = 0; j < 4; ++j) {
        r.u[j]     = f2bf1(bf2f(x0[j])  * a0 + bf2f(x1[j])  * a1);
        r.u[4 + j] = f2bf1(bf2f(x0b[j]) * a0 + bf2f(x1b[j]) * a1);
    }
    *(short8*)(cb + off) = r.s;
}

// ---------------------------------------------------------------------------
extern "C" void kernel_launch(void* const* d_in, const int* in_sizes, int n_in,
                              void* d_out, int out_size, void* d_ws, size_t ws_size,
                              hipStream_t stream) {
    const float* query = (const float*)d_in[0];
    const float* key   = (const float*)d_in[1];
    const float* value = (const float*)d_in[2];
    const float* Wq = (const float*)d_in[3];
    const float* bq = (const float*)d_in[4];
    const float* Wk = (const float*)d_in[5];
    const float* bk = (const float*)d_in[6];
    const float* Wv = (const float*)d_in[7];
    const float* bv = (const float*)d_in[8];
    const float* Wo = (const float*)d_in[9];
    const float* bo = (const float*)d_in[10];
    float* out = (float*)d_out;

    const size_t mat = (size_t)MTOT * D_MODEL;      // 3.145M elems
    unsigned short* qb  = (unsigned short*)d_ws;    // projected Q/K/V (bf16)
    unsigned short* kb  = qb + mat;
    unsigned short* vb  = kb + mat;
    unsigned short* cb  = vb + mat;                 // combined context (bf16)
    unsigned short* Wqt = cb + mat;                 // transposed bf16 weights
    unsigned short* Wkt = Wqt + (size_t)D_MODEL * D_MODEL;
    unsigned short* Wvt = Wkt + (size_t)D_MODEL * D_MODEL;
    unsigned short* Wot = Wvt + (size_t)D_MODEL * D_MODEL;
    unsigned short* op  = Wot + (size_t)D_MODEL * D_MODEL;   // o partials x2
    float*          mp  = (float*)(op + 2 * mat);            // m partials x2
    float*          lp  = mp + 2 * (size_t)MTOT * HEADS;     // l partials x2

    cvt_wt_k<<<dim3(D_MODEL / 32, D_MODEL / 32, 4), 256, 0, stream>>>(
        Wq, Wk, Wv, Wo, Wqt, Wkt, Wvt, Wot);

    gemm_qkv_k<<<dim3(576), 512, 0, stream>>>(
        query, key, value, Wqt, Wkt, Wvt, bq, bk, bv, qb, kb, vb);

    attn_mfma_k<<<dim3(768), 256, 0, stream>>>(qb, kb, vb, op, mp, lp);

    combine_k<<<dim3(MTOT * D_MODEL / 8 / 256), 256, 0, stream>>>(op, mp, lp, cb);

    gemm_o_k<<<dim3(768), 256, 0, stream>>>(cb, Wot, bo, out);
}